// Round 4
// baseline (602.974 us; speedup 1.0000x reference)
//
#include <hip/hip_runtime.h>

#define NPIX 16384
#define WIDTH 128
#define APT 16               // A-points per thread
#define ABLK (256 * APT)     // 4096 A-points per block
#define JLEN 64              // B-points per block tile
#define GY (NPIX / JLEN)     // 256

typedef float v2f __attribute__((ext_vector_type(2)));

// order-monotone float <-> uint key (for exact atomicMin on float values)
__device__ __forceinline__ unsigned fkey(float f) {
    unsigned u = __float_as_uint(f);
    return (u & 0x80000000u) ? ~u : (u | 0x80000000u);
}
__device__ __forceinline__ float funkey(unsigned k) {
    return __uint_as_float((k & 0x80000000u) ? (k ^ 0x80000000u) : ~k);
}

__device__ __forceinline__ v2f splat2(float x) { v2f r; r.x = x; r.y = x; return r; }

// depth -> (x, y, z, |p|^2 + inf_add). Same math as reference pixel2xyz.
__device__ __forceinline__ float4 make_point(float d, int p,
    float fu, float cu, float p03, float fv, float cv, float p13, float p23,
    float inf_add) {
    float px = (float)(p & (WIDTH - 1));
    float py = (float)(p >> 7);
    float x = (px * (d + p23) - (cu * d + p03)) / fu;
    float y = (py * (d + p23) - (cv * d + p13)) / fv;
    float s = x * x + y * y + d * d;
    return make_float4(x, y, d, s + inf_add);
}

// ---------------------------------------------------------------------------
// Pairwise-min kernel. Each block: 4096 A-points (16/thread in regs, -2x
// folded), one 64-point B tile in LDS stored SoA (broadcast float2 reads).
// blockIdx.z picks direction. Inner op per 2 B-points: 3 packed FMA
// (v_pk_fma_f32) + 1 min3. Results merged globally via atomicMin on
// order-monotone uint keys (exact, order-independent -> deterministic).
// Invalid pixels (target<=0) carry +1e30 in b.w -> masked pairs lose the min.
// ---------------------------------------------------------------------------
__global__ __launch_bounds__(256, 5) void pair_min_kernel(
    const float* __restrict__ pred,
    const float* __restrict__ target,
    const float* __restrict__ P,
    unsigned* __restrict__ pmk) {
    float fu = P[0], cu = P[2], p03 = P[3];
    float fv = P[5], cv = P[6], p13 = P[7], p23 = P[11];

    const float* __restrict__ dA;
    const float* __restrict__ dB;
    unsigned* __restrict__ pm;
    if (blockIdx.z == 0) { dA = target; dB = pred;   pm = pmk; }
    else                 { dA = pred;   dB = target; pm = pmk + NPIX; }

    __shared__ float sBx[JLEN], sBy[JLEN], sBz[JLEN], sBw[JLEN];
    int t = threadIdx.x;

    if (t < JLEN) {
        int jb = blockIdx.y * JLEN + t;
        float db = dB[jb];
        float tb = target[jb];
        float inf_add = (tb > 0.0f) ? 0.0f : 1e30f;
        float4 b = make_point(db, jb, fu, cu, p03, fv, cv, p13, p23, inf_add);
        sBx[t] = b.x; sBy[t] = b.y; sBz[t] = b.z; sBw[t] = b.w;
    }

    // A points: 16 per thread, fold -2 in (|a|^2 added back in reduce)
    int abase = blockIdx.x * ABLK + t;
    float ax[APT], ay[APT], az[APT], mn[APT];
    #pragma unroll
    for (int k = 0; k < APT; ++k) {
        int a = abase + k * 256;
        float da = dA[a];
        float4 pa = make_point(da, a, fu, cu, p03, fv, cv, p13, p23, 0.0f);
        ax[k] = -2.0f * pa.x;
        ay[k] = -2.0f * pa.y;
        az[k] = -2.0f * pa.z;
        mn[k] = 3e38f;
    }
    __syncthreads();

    #pragma unroll 2
    for (int j = 0; j < JLEN; j += 2) {
        v2f bx = *(const v2f*)&sBx[j];
        v2f by = *(const v2f*)&sBy[j];
        v2f bz = *(const v2f*)&sBz[j];
        v2f bw = *(const v2f*)&sBw[j];
        #pragma unroll
        for (int k = 0; k < APT; ++k) {
            v2f e = __builtin_elementwise_fma(splat2(ax[k]), bx,
                    __builtin_elementwise_fma(splat2(ay[k]), by,
                    __builtin_elementwise_fma(splat2(az[k]), bz, bw)));
            mn[k] = fminf(mn[k], fminf(e.x, e.y)); // -> v_min3_f32
        }
    }

    #pragma unroll
    for (int k = 0; k < APT; ++k)
        atomicMin(&pm[abase + k * 256], fkey(mn[k]));
}

// ---------------------------------------------------------------------------
// Reduce: decode keys, add back |a|^2, masked sum (deterministic order).
// ---------------------------------------------------------------------------
__global__ __launch_bounds__(256) void reduce_kernel(
    const unsigned* __restrict__ pmk,
    const float* __restrict__ pred,
    const float* __restrict__ target,
    const float* __restrict__ P,
    float* __restrict__ bsum,
    float* __restrict__ bn) {
    int t = threadIdx.x;
    int a = blockIdx.x * 256 + t;

    float m12 = funkey(pmk[a]);
    float m21 = funkey(pmk[NPIX + a]);

    float fu = P[0], cu = P[2], p03 = P[3];
    float fv = P[5], cv = P[6], p13 = P[7], p23 = P[11];
    float dt = target[a], dp = pred[a];
    float v = (dt > 0.0f) ? 1.0f : 0.0f;
    float4 pT = make_point(dt, a, fu, cu, p03, fv, cv, p13, p23, 0.0f);
    float4 pP = make_point(dp, a, fu, cu, p03, fv, cv, p13, p23, 0.0f);
    float contrib = v * ((m12 + pT.w) + (m21 + pP.w));

    for (int o = 32; o > 0; o >>= 1) {
        contrib += __shfl_down(contrib, o);
        v += __shfl_down(v, o);
    }
    __shared__ float ls[8];
    int wid = t >> 6, lane = t & 63;
    if (lane == 0) { ls[wid] = contrib; ls[wid + 4] = v; }
    __syncthreads();
    if (t == 0) {
        bsum[blockIdx.x] = (ls[0] + ls[1]) + (ls[2] + ls[3]);
        bn[blockIdx.x]   = (ls[4] + ls[5]) + (ls[6] + ls[7]);
    }
}

// ---------------------------------------------------------------------------
// Final: fixed-order lane-parallel sum of 64 partials (deterministic).
// ---------------------------------------------------------------------------
__global__ void final_kernel(const float* __restrict__ bsum,
                             const float* __restrict__ bn,
                             float* __restrict__ out) {
    int t = threadIdx.x; // 64 threads
    float s = bsum[t], n = bn[t];
    for (int o = 32; o > 0; o >>= 1) {
        s += __shfl_down(s, o);
        n += __shfl_down(n, o);
    }
    if (t == 0) out[0] = s / n;
}

extern "C" void kernel_launch(void* const* d_in, const int* in_sizes, int n_in,
                              void* d_out, int out_size, void* d_ws, size_t ws_size,
                              hipStream_t stream) {
    const float* pred   = (const float*)d_in[0];
    const float* target = (const float*)d_in[1];
    const float* P      = (const float*)d_in[2];
    float* out = (float*)d_out;

    char* ws = (char*)d_ws;
    unsigned* pmk = (unsigned*)ws;                       // 2*NPIX uints
    float* bsum = (float*)(ws + (size_t)2 * NPIX * 4);   // 64 floats
    float* bn   = bsum + 64;

    hipMemsetAsync(pmk, 0xFF, (size_t)2 * NPIX * 4, stream); // keys = +inf

    dim3 grid(NPIX / ABLK, GY, 2); // (4, 256, 2) = 2048 blocks
    pair_min_kernel<<<grid, 256, 0, stream>>>(pred, target, P, pmk);

    reduce_kernel<<<dim3(NPIX / 256), 256, 0, stream>>>(pmk, pred, target, P, bsum, bn);
    final_kernel<<<1, 64, 0, stream>>>(bsum, bn, out);
}

// Round 5
// 76.269 us; speedup vs baseline: 7.9059x; 7.9059x over previous
//
#include <hip/hip_runtime.h>

#define NPIX 16384
#define WIDTH 128
#define JC 64            // j-slices
#define JLEN (NPIX / JC) // 256 B-points per block
#define APT 4            // A-points per thread
#define ABLK (256 * APT) // 1024 A-points per block

// depth -> (x, y, z, |p|^2 + inf_add). Same math as reference pixel2xyz.
__device__ __forceinline__ float4 make_point(float d, int p,
    float fu, float cu, float p03, float fv, float cv, float p13, float p23,
    float inf_add) {
    float px = (float)(p & (WIDTH - 1));
    float py = (float)(p >> 7);
    float x = (px * (d + p23) - (cu * d + p03)) / fu;
    float y = (py * (d + p23) - (cv * d + p13)) / fv;
    float s = x * x + y * y + d * d;
    return make_float4(x, y, d, s + inf_add);
}

// ---------------------------------------------------------------------------
// Kernel 1: depth -> point clouds. .w = |p|^2 (+1e30 if target<=0, the B-side
// mask: masked pairs lose the min; A-side invalid rows are masked in reduce).
// ---------------------------------------------------------------------------
__global__ __launch_bounds__(256) void pc_precompute_kernel(
    const float* __restrict__ pred,
    const float* __restrict__ target,
    const float* __restrict__ P,
    float4* __restrict__ pcT,
    float4* __restrict__ pcP) {
    int p = blockIdx.x * blockDim.x + threadIdx.x;
    float fu = P[0], cu = P[2], p03 = P[3];
    float fv = P[5], cv = P[6], p13 = P[7], p23 = P[11];
    float dt = target[p];
    float dp = pred[p];
    float inf_add = (dt > 0.0f) ? 0.0f : 1e30f;
    pcT[p] = make_point(dt, p, fu, cu, p03, fv, cv, p13, p23, inf_add);
    pcP[p] = make_point(dp, p, fu, cu, p03, fv, cv, p13, p23, inf_add);
}

// ---------------------------------------------------------------------------
// Kernel 2: pairwise min, B via wave-uniform (scalar-cache) loads — no LDS.
// Each block: 1024 A-points (4/thread in regs, -2 folded), 256 B-points
// streamed at uniform addresses (s_load_dwordx4). Inner op per 2 B: 6 FMA +
// 1 min3. |a|^2 added back in reduce. Partial mins written once (no atomics
// -- R4 showed device-scope atomicMin generates GBs of coherence traffic).
// ---------------------------------------------------------------------------
__global__ __launch_bounds__(256, 8) void pair_min_kernel(
    const float4* __restrict__ pcT,
    const float4* __restrict__ pcP,
    float* __restrict__ pm12,
    float* __restrict__ pm21) {
    const float4* __restrict__ A;
    const float4* __restrict__ B;
    float* __restrict__ pm;
    if (blockIdx.z == 0) { A = pcT; B = pcP; pm = pm12; }
    else                 { A = pcP; B = pcT; pm = pm21; }

    int t = threadIdx.x;
    int abase = blockIdx.x * ABLK + t;

    float ax[APT], ay[APT], az[APT], mn[APT];
    #pragma unroll
    for (int k = 0; k < APT; ++k) {
        float4 a = A[abase + k * 256];
        ax[k] = -2.0f * a.x;
        ay[k] = -2.0f * a.y;
        az[k] = -2.0f * a.z;
        mn[k] = 3e38f;
    }

    const float4* __restrict__ Bt = B + blockIdx.y * JLEN; // uniform base

    #pragma unroll 2
    for (int j = 0; j < JLEN; j += 2) {
        float4 b0 = Bt[j];     // uniform address -> scalar load
        float4 b1 = Bt[j + 1];
        #pragma unroll
        for (int k = 0; k < APT; ++k) {
            float e0 = fmaf(ax[k], b0.x, fmaf(ay[k], b0.y, fmaf(az[k], b0.z, b0.w)));
            float e1 = fmaf(ax[k], b1.x, fmaf(ay[k], b1.y, fmaf(az[k], b1.z, b1.w)));
            mn[k] = fminf(mn[k], fminf(e0, e1)); // -> v_min3_f32
        }
    }

    int obase = blockIdx.y * NPIX + abase;
    #pragma unroll
    for (int k = 0; k < APT; ++k) pm[obase + k * 256] = mn[k];
}

// ---------------------------------------------------------------------------
// Kernel 3: reduce. 256 blocks; each owns 64 A-points, threads split the JC
// slices 4-way (min exactly associative), LDS-combine, |a|^2 add-back,
// masked deterministic sum.
// ---------------------------------------------------------------------------
__global__ __launch_bounds__(256) void reduce_kernel(
    const float* __restrict__ pm12,
    const float* __restrict__ pm21,
    const float4* __restrict__ pcT,
    const float4* __restrict__ pcP,
    const float* __restrict__ target,
    float* __restrict__ bsum,
    float* __restrict__ bn) {
    int t = threadIdx.x;
    int al = t & 63, q = t >> 6;
    int a = blockIdx.x * 64 + al;

    float m12 = 3e38f, m21 = 3e38f;
    int jc0 = q * (JC / 4);
    for (int jc = jc0; jc < jc0 + JC / 4; ++jc) {
        m12 = fminf(m12, pm12[jc * NPIX + a]);
        m21 = fminf(m21, pm21[jc * NPIX + a]);
    }
    __shared__ float s12[4][64], s21[4][64];
    s12[q][al] = m12;
    s21[q][al] = m21;
    __syncthreads();

    if (t < 64) {
        m12 = fminf(fminf(s12[0][t], s12[1][t]), fminf(s12[2][t], s12[3][t]));
        m21 = fminf(fminf(s21[0][t], s21[1][t]), fminf(s21[2][t], s21[3][t]));

        float v = (target[a] > 0.0f) ? 1.0f : 0.0f;
        // valid a: .w fields are clean |p|^2; invalid a: masked by v=0
        float contrib = v * ((m12 + pcT[a].w) + (m21 + pcP[a].w));

        for (int o = 32; o > 0; o >>= 1) {
            contrib += __shfl_down(contrib, o);
            v += __shfl_down(v, o);
        }
        if (t == 0) {
            bsum[blockIdx.x] = contrib;
            bn[blockIdx.x] = v;
        }
    }
}

// ---------------------------------------------------------------------------
// Kernel 4: fixed-order lane-parallel sum of 256 partials (deterministic).
// ---------------------------------------------------------------------------
__global__ void final_kernel(const float* __restrict__ bsum,
                             const float* __restrict__ bn,
                             float* __restrict__ out) {
    int t = threadIdx.x; // 64 threads
    float s = 0.0f, n = 0.0f;
    for (int i = t; i < 256; i += 64) { s += bsum[i]; n += bn[i]; }
    for (int o = 32; o > 0; o >>= 1) {
        s += __shfl_down(s, o);
        n += __shfl_down(n, o);
    }
    if (t == 0) out[0] = s / n;
}

extern "C" void kernel_launch(void* const* d_in, const int* in_sizes, int n_in,
                              void* d_out, int out_size, void* d_ws, size_t ws_size,
                              hipStream_t stream) {
    const float* pred   = (const float*)d_in[0];
    const float* target = (const float*)d_in[1];
    const float* P      = (const float*)d_in[2];
    float* out = (float*)d_out;

    char* ws = (char*)d_ws;
    float4* pcT = (float4*)ws;                            // NPIX float4
    float4* pcP = (float4*)(ws + (size_t)NPIX * 16);
    float* pm12 = (float*)(ws + (size_t)NPIX * 32);       // JC*NPIX floats
    float* pm21 = pm12 + (size_t)JC * NPIX;
    float* bsum = pm21 + (size_t)JC * NPIX;               // 256 + 256
    float* bn   = bsum + 256;

    pc_precompute_kernel<<<dim3(NPIX / 256), 256, 0, stream>>>(pred, target, P, pcT, pcP);

    dim3 grid(NPIX / ABLK, JC, 2); // (16, 64, 2) = 2048 blocks
    pair_min_kernel<<<grid, 256, 0, stream>>>(pcT, pcP, pm12, pm21);

    reduce_kernel<<<dim3(256), 256, 0, stream>>>(pm12, pm21, pcT, pcP, target, bsum, bn);
    final_kernel<<<1, 64, 0, stream>>>(bsum, bn, out);
}

// Round 6
// 63.596 us; speedup vs baseline: 9.4813x; 1.1993x over previous
//
#include <hip/hip_runtime.h>

#define NPIX 16384
#define WIDTH 128
#define APT 8            // A-points per thread
#define ABLK (256 * APT) // 2048 A-points per block
#define TILE 128         // B-points staged per LDS tile

typedef float v2f __attribute__((ext_vector_type(2)));

__device__ __forceinline__ v2f splat2(float x) { v2f r; r.x = x; r.y = x; return r; }

// depth -> (x, y, z, |p|^2 + inf_add). Same math as reference pixel2xyz.
__device__ __forceinline__ float4 make_point(float d, int p,
    float fu, float cu, float p03, float fv, float cv, float p13, float p23,
    float inf_add) {
    float px = (float)(p & (WIDTH - 1));
    float py = (float)(p >> 7);
    float x = (px * (d + p23) - (cu * d + p03)) / fu;
    float y = (py * (d + p23) - (cv * d + p13)) / fv;
    float s = x * x + y * y + d * d;
    return make_float4(x, y, d, s + inf_add);
}

// ---------------------------------------------------------------------------
// Pairwise-min kernel (precompute fused). Each block: 2048 A-points
// (8/thread; -2 folded and pre-splatted into v2f regs once — loop-invariant,
// so no per-iteration movs and no SGPR-operand hazards). B staged in LDS
// pair-interleaved: sP0[p]=(b0x,b1x,b0y,b1y), sP1[p]=(b0z,b1z,b0w,b1w), so
// 2 broadcast ds_read_b128 feed 3 v_pk_fma_f32 + 1 v_min3_f32 per A-point
// (2 instr/pair). Invalid pixels (target<=0) carry +1e30 in w -> masked
// pairs lose the min. |a|^2 is added back in the reduce kernel.
// ---------------------------------------------------------------------------
__global__ __launch_bounds__(256, 4) void pair_min_kernel(
    const float* __restrict__ pred,
    const float* __restrict__ target,
    const float* __restrict__ P,
    float* __restrict__ pm12,
    float* __restrict__ pm21,
    int jlen) {
    float fu = P[0], cu = P[2], p03 = P[3];
    float fv = P[5], cv = P[6], p13 = P[7], p23 = P[11];

    const float* __restrict__ dA;
    const float* __restrict__ dB;
    float* __restrict__ pm;
    if (blockIdx.z == 0) { dA = target; dB = pred;   pm = pm12; }
    else                 { dA = pred;   dB = target; pm = pm21; }

    __shared__ float sP0f[TILE * 2]; // (b0x,b1x,b0y,b1y) per pair
    __shared__ float sP1f[TILE * 2]; // (b0z,b1z,b0w,b1w) per pair
    int t = threadIdx.x;

    // A points: 8 per thread; fold -2; pre-splat coords into v2f registers.
    int abase = blockIdx.x * ABLK + t;
    v2f ax2[APT], ay2[APT], az2[APT];
    float mn[APT];
    #pragma unroll
    for (int k = 0; k < APT; ++k) {
        int a = abase + k * 256;
        float4 pa = make_point(dA[a], a, fu, cu, p03, fv, cv, p13, p23, 0.0f);
        ax2[k] = splat2(-2.0f * pa.x);
        ay2[k] = splat2(-2.0f * pa.y);
        az2[k] = splat2(-2.0f * pa.z);
        mn[k] = 3e38f;
    }

    int jbase = blockIdx.y * jlen;
    for (int jt = 0; jt < jlen; jt += TILE) {
        __syncthreads();
        if (t < TILE) {
            int jb = jbase + jt + t;
            float tb = target[jb];
            float inf_add = (tb > 0.0f) ? 0.0f : 1e30f;
            float4 b = make_point(dB[jb], jb, fu, cu, p03, fv, cv, p13, p23, inf_add);
            int q = t >> 1, r = t & 1;
            sP0f[4 * q + r]     = b.x;
            sP0f[4 * q + 2 + r] = b.y;
            sP1f[4 * q + r]     = b.z;
            sP1f[4 * q + 2 + r] = b.w;
        }
        __syncthreads();

        #pragma unroll 2
        for (int p = 0; p < TILE / 2; ++p) {
            float4 c0 = ((const float4*)sP0f)[p]; // broadcast b128
            float4 c1 = ((const float4*)sP1f)[p];
            v2f bx, by, bz, bw;
            bx.x = c0.x; bx.y = c0.y;
            by.x = c0.z; by.y = c0.w;
            bz.x = c1.x; bz.y = c1.y;
            bw.x = c1.z; bw.y = c1.w;
            #pragma unroll
            for (int k = 0; k < APT; ++k) {
                v2f e = __builtin_elementwise_fma(ax2[k], bx,
                        __builtin_elementwise_fma(ay2[k], by,
                        __builtin_elementwise_fma(az2[k], bz, bw)));
                mn[k] = fminf(fminf(e.x, e.y), mn[k]); // -> v_min3_f32
            }
        }
    }

    int obase = blockIdx.y * NPIX + abase;
    #pragma unroll
    for (int k = 0; k < APT; ++k) pm[obase + k * 256] = mn[k];
}

// ---------------------------------------------------------------------------
// Reduce: 256 blocks; each owns 64 A-points, threads split the JC slices
// 4-way (min exactly associative), LDS-combine, |a|^2 add-back, masked
// deterministic sum. Recomputes |a|^2 from depth (cheap, avoids pc arrays).
// ---------------------------------------------------------------------------
__global__ __launch_bounds__(256) void reduce_kernel(
    const float* __restrict__ pm12,
    const float* __restrict__ pm21,
    const float* __restrict__ pred,
    const float* __restrict__ target,
    const float* __restrict__ P,
    int jc,
    float* __restrict__ bsum,
    float* __restrict__ bn) {
    int t = threadIdx.x;
    int al = t & 63, q = t >> 6;
    int a = blockIdx.x * 64 + al;

    float m12 = 3e38f, m21 = 3e38f;
    int per = jc >> 2;
    int jc0 = q * per;
    for (int j = jc0; j < jc0 + per; ++j) {
        m12 = fminf(m12, pm12[j * NPIX + a]);
        m21 = fminf(m21, pm21[j * NPIX + a]);
    }
    __shared__ float s12[4][64], s21[4][64];
    s12[q][al] = m12;
    s21[q][al] = m21;
    __syncthreads();

    if (t < 64) {
        m12 = fminf(fminf(s12[0][t], s12[1][t]), fminf(s12[2][t], s12[3][t]));
        m21 = fminf(fminf(s21[0][t], s21[1][t]), fminf(s21[2][t], s21[3][t]));

        float fu = P[0], cu = P[2], p03 = P[3];
        float fv = P[5], cv = P[6], p13 = P[7], p23 = P[11];
        float dt = target[a], dp = pred[a];
        float v = (dt > 0.0f) ? 1.0f : 0.0f;
        float4 pT = make_point(dt, a, fu, cu, p03, fv, cv, p13, p23, 0.0f);
        float4 pP = make_point(dp, a, fu, cu, p03, fv, cv, p13, p23, 0.0f);
        float contrib = v * ((m12 + pT.w) + (m21 + pP.w));

        for (int o = 32; o > 0; o >>= 1) {
            contrib += __shfl_down(contrib, o);
            v += __shfl_down(v, o);
        }
        if (t == 0) {
            bsum[blockIdx.x] = contrib;
            bn[blockIdx.x] = v;
        }
    }
}

// ---------------------------------------------------------------------------
// Final: fixed-order lane-parallel sum of 256 partials (deterministic).
// ---------------------------------------------------------------------------
__global__ void final_kernel(const float* __restrict__ bsum,
                             const float* __restrict__ bn,
                             float* __restrict__ out) {
    int t = threadIdx.x; // 64 threads
    float s = 0.0f, n = 0.0f;
    for (int i = t; i < 256; i += 64) { s += bsum[i]; n += bn[i]; }
    for (int o = 32; o > 0; o >>= 1) {
        s += __shfl_down(s, o);
        n += __shfl_down(n, o);
    }
    if (t == 0) out[0] = s / n;
}

extern "C" void kernel_launch(void* const* d_in, const int* in_sizes, int n_in,
                              void* d_out, int out_size, void* d_ws, size_t ws_size,
                              hipStream_t stream) {
    const float* pred   = (const float*)d_in[0];
    const float* target = (const float*)d_in[1];
    const float* P      = (const float*)d_in[2];
    float* out = (float*)d_out;

    // choose J-slice count that fits the workspace (deterministic given ws_size)
    int JC = 128;
    while (JC > 1 && (size_t)2 * JC * NPIX * 4 + 2048 > ws_size) JC >>= 1;

    char* ws = (char*)d_ws;
    float* pm12 = (float*)ws;                 // JC*NPIX floats
    float* pm21 = pm12 + (size_t)JC * NPIX;
    float* bsum = pm21 + (size_t)JC * NPIX;   // 256 + 256
    float* bn   = bsum + 256;

    int jlen = NPIX / JC;
    dim3 grid(NPIX / ABLK, JC, 2); // (8, 128, 2) = 2048 blocks at JC=128
    pair_min_kernel<<<grid, 256, 0, stream>>>(pred, target, P, pm12, pm21, jlen);

    reduce_kernel<<<dim3(256), 256, 0, stream>>>(pm12, pm21, pred, target, P, JC, bsum, bn);
    final_kernel<<<1, 64, 0, stream>>>(bsum, bn, out);
}